// Round 7
// baseline (115.440 us; speedup 1.0000x reference)
//
#include <hip/hip_runtime.h>
#include <math.h>

#define NL    4096      // coarse points
#define NH    16384     // fine points
#define NF4   64        // 256 features / 4
#define FPB   64        // fine points per block group (lane = fine point)

// ---- split-scan path params ----
#define BLKA  1024      // scan kernel threads (16 waves)
#define NWA   16
#define NHALF 2048      // candidates per scan block
#define SLICE 128       // candidates per wave (NHALF / NWA)
// ---- fallback (round-5) params ----
#define BLKF  1024
#define NWF   16
#define PERWF (NL / NWF)

typedef float v16f __attribute__((ext_vector_type(16)));
typedef float v2f  __attribute__((ext_vector_type(2)));

// Sorted top-3 insert: min/med3 for values, cmps + cndmasks for indices.
// Strict < keeps earliest index on ties (candidates arrive in ascending index
// order within a set) — matches jax.lax.top_k stability.
__device__ __forceinline__ void ins3(float d, int j,
    float& b0, float& b1, float& b2, int& i0, int& i1, int& i2)
{
  const bool p0 = d < b0;
  const bool p1 = d < b1;
  const bool p2 = d < b2;
  const int ni0 = p0 ? j : i0;
  const int ni1 = p0 ? i0 : (p1 ? j : i1);
  const int ni2 = p1 ? i1 : (p2 ? j : i2);
  const float nb0 = fminf(b0, d);
  const float nb1 = __builtin_amdgcn_fmed3f(d, b0, b1);
  const float nb2 = __builtin_amdgcn_fmed3f(d, b1, b2);
  b0 = nb0; b1 = nb1; b2 = nb2;
  i0 = ni0; i1 = ni1; i2 = ni2;
}

// Lexicographic (d, j) insert — merging lists whose index order is arbitrary.
__device__ __forceinline__ void lexins3(float d, int j,
    float& b0, float& b1, float& b2, int& i0, int& i1, int& i2)
{
  bool s2 = (d < b2) || ((d == b2) && (j < i2));
  b2 = s2 ? d : b2;  i2 = s2 ? j : i2;
  bool s1 = (b2 < b1) || ((b2 == b1) && (i2 < i1));
  float tf = b1; int ti = i1;
  b1 = s1 ? b2 : b1;  i1 = s1 ? i2 : i1;
  b2 = s1 ? tf : b2;  i2 = s1 ? ti : i2;
  bool s0 = (b1 < b0) || ((b1 == b0) && (i1 < i0));
  tf = b0; ti = i0;
  b0 = s0 ? b1 : b0;  i0 = s0 ? i1 : i0;
  b1 = s0 ? tf : b1;  i1 = s0 ? ti : i1;
}

// Packed distance for 2 adjacent candidates. Per-component rounding is
// BIT-IDENTICAL to the scalar reference sequence:
//   dot = fma(h2,lz, fma(h1,ly, mul(h0,lx)))
//   d2  = add( fma(dot,-2,hh), ll )   [fma == sub(hh,mul(2,dot)) since 2*dot exact]
__device__ __forceinline__ v2f dist2_pk(v2f lx, v2f ly, v2f lz, v2f ll,
                                        v2f h00, v2f h11, v2f h22, v2f hhh,
                                        v2f m22)
{
  v2f d;
  asm("v_pk_mul_f32 %0, %1, %2\n\t"
      "v_pk_fma_f32 %0, %3, %4, %0\n\t"
      "v_pk_fma_f32 %0, %5, %6, %0\n\t"
      "v_pk_fma_f32 %0, %0, %7, %8\n\t"
      "v_pk_add_f32 %0, %0, %9"
      : "=&v"(d)
      : "v"(h00), "s"(lx), "v"(h11), "s"(ly), "v"(h22), "s"(lz),
        "v"(m22), "v"(hhh), "s"(ll));
  return d;
}

// ---------- prologue: SoA pack (x | y | z | ll), exact np rounding ----------
__global__ __launch_bounds__(256)
void prep_soa_kernel(const float* __restrict__ pos_l, float* __restrict__ cand)
{
  const int i = blockIdx.x * 256 + threadIdx.x;   // 0..NL-1
  const float l0 = pos_l[i * 3 + 0];
  const float l1 = pos_l[i * 3 + 1];
  const float l2 = pos_l[i * 3 + 2];
  const float ll = __fadd_rn(__fadd_rn(__fmul_rn(l0, l0), __fmul_rn(l1, l1)),
                             __fmul_rn(l2, l2));
  cand[i]          = l0;
  cand[NL + i]     = l1;
  cand[2 * NL + i] = l2;
  cand[3 * NL + i] = ll;
}

// ---------- scan: 512 blocks (2/CU), each scans NHALF candidates ----------
__global__ __launch_bounds__(BLKA)
void knn_scan_kernel(const float* __restrict__ pos_h,
                     const float* __restrict__ cand,    // SoA, 4*NL floats
                     float* __restrict__ pdist,         // [2*NH*3]
                     int*   __restrict__ pidx)          // [2*NH*3]
{
  __shared__ float pd[NWA * FPB * 3];   // 12 KB
  __shared__ int   pj[NWA * FPB * 3];   // 12 KB

  const int tid  = threadIdx.x;
  const int lane = tid & 63;
  const int wv   = __builtin_amdgcn_readfirstlane(tid >> 6);
  const int half = blockIdx.x & 1;
  const int fgrp = blockIdx.x >> 1;
  const int fg   = fgrp * FPB + lane;

  const float h0 = pos_h[fg * 3 + 0];
  const float h1 = pos_h[fg * 3 + 1];
  const float h2 = pos_h[fg * 3 + 2];
  const float hh = __fadd_rn(__fadd_rn(__fmul_rn(h0, h0), __fmul_rn(h1, h1)),
                             __fmul_rn(h2, h2));
  const v2f h00 = { h0, h0 }, h11 = { h1, h1 }, h22 = { h2, h2 };
  const v2f hhh = { hh, hh }, m22 = { -2.0f, -2.0f };

  // two independent top-3 sets: a = even pair-slots, c = odd (both ascending j)
  float a0 = INFINITY, a1 = INFINITY, a2 = INFINITY;  int ai0 = 0, ai1 = 0, ai2 = 0;
  float c0 = INFINITY, c1 = INFINITY, c2 = INFINITY;  int ci0 = 0, ci1 = 0, ci2 = 0;

  const int jbase = __builtin_amdgcn_readfirstlane(half * NHALF + wv * SLICE);

  for (int t = 0; t < SLICE; t += 16) {
    // 16 candidates: one dwordx16 per SoA array (arrays are NL*4 = 0x4000 apart)
    v16f sx, sy, sz, sw;
    const float* p = cand + jbase + t;   // wave-uniform
    asm volatile("s_load_dwordx16 %0, %4, 0x0\n\t"
                 "s_load_dwordx16 %1, %4, 0x4000\n\t"
                 "s_load_dwordx16 %2, %4, 0x8000\n\t"
                 "s_load_dwordx16 %3, %4, 0xc000"
                 : "=&s"(sx), "=&s"(sy), "=&s"(sz), "=&s"(sw)
                 : "s"(p));
    asm volatile("s_waitcnt lgkmcnt(0)"
                 : "+s"(sx), "+s"(sy), "+s"(sz), "+s"(sw));

    #pragma unroll
    for (int pr = 0; pr < 8; ++pr) {
      const v2f lx = { sx[2 * pr], sx[2 * pr + 1] };
      const v2f ly = { sy[2 * pr], sy[2 * pr + 1] };
      const v2f lz = { sz[2 * pr], sz[2 * pr + 1] };
      const v2f lw = { sw[2 * pr], sw[2 * pr + 1] };
      const v2f d  = dist2_pk(lx, ly, lz, lw, h00, h11, h22, hhh, m22);
      ins3(d.x, jbase + t + 2 * pr,     a0, a1, a2, ai0, ai1, ai2);
      ins3(d.y, jbase + t + 2 * pr + 1, c0, c1, c2, ci0, ci1, ci2);
    }
  }

  // merge set c into set a (cross-set order arbitrary -> lex)
  lexins3(c0, ci0, a0, a1, a2, ai0, ai1, ai2);
  lexins3(c1, ci1, a0, a1, a2, ai0, ai1, ai2);
  lexins3(c2, ci2, a0, a1, a2, ai0, ai1, ai2);

  {
    const int s = (wv * FPB + lane) * 3;
    pd[s + 0] = a0; pd[s + 1] = a1; pd[s + 2] = a2;
    pj[s + 0] = ai0; pj[s + 1] = ai1; pj[s + 2] = ai2;
  }
  __syncthreads();

  if (tid < FPB) {
    float b0 = INFINITY, b1 = INFINITY, b2 = INFINITY;
    int   i0 = 0x7fffffff, i1 = 0x7fffffff, i2 = 0x7fffffff;
    for (int w = 0; w < NWA; ++w) {
      const int s = (w * FPB + tid) * 3;
      lexins3(pd[s + 0], pj[s + 0], b0, b1, b2, i0, i1, i2);
      lexins3(pd[s + 1], pj[s + 1], b0, b1, b2, i0, i1, i2);
      lexins3(pd[s + 2], pj[s + 2], b0, b1, b2, i0, i1, i2);
    }
    const int o = (half * NH + fgrp * FPB + tid) * 3;
    pdist[o + 0] = b0; pdist[o + 1] = b1; pdist[o + 2] = b2;
    pidx[o + 0]  = i0; pidx[o + 1]  = i1; pidx[o + 2]  = i2;
  }
}

// ---------- finish: merge 2 partial lists, weights, interpolate ----------
__global__ __launch_bounds__(1024)
void knn_finish_kernel(const float* __restrict__ x,
                       const float* __restrict__ pos_l,
                       const float* __restrict__ pos_h,
                       const float* __restrict__ pdist,
                       const int*   __restrict__ pidx,
                       float* __restrict__ out)
{
  __shared__ float wn[FPB * 3];
  __shared__ int   sj[FPB * 3];
  const int tid = threadIdx.x;

  if (tid < FPB) {
    const int f  = blockIdx.x * FPB + tid;
    const int o0 = f * 3;
    const int o1 = (NH + f) * 3;
    float b0 = pdist[o0], b1 = pdist[o0 + 1], b2 = pdist[o0 + 2];
    int   i0 = pidx[o0],  i1 = pidx[o0 + 1],  i2 = pidx[o0 + 2];
    lexins3(pdist[o1],     pidx[o1],     b0, b1, b2, i0, i1, i2);
    lexins3(pdist[o1 + 1], pidx[o1 + 1], b0, b1, b2, i0, i1, i2);
    lexins3(pdist[o1 + 2], pidx[o1 + 2], b0, b1, b2, i0, i1, i2);

    const float H0 = pos_h[f * 3 + 0];
    const float H1 = pos_h[f * 3 + 1];
    const float H2 = pos_h[f * 3 + 2];
    float wk[3];
    int   jk[3] = { i0, i1, i2 };
    #pragma unroll
    for (int k = 0; k < 3; ++k) {
      const int j = jk[k];
      // exact recompute per reference: diff, squares, sequential sum (no fma)
      const float dx = __fsub_rn(H0, pos_l[j * 3 + 0]);
      const float dy = __fsub_rn(H1, pos_l[j * 3 + 1]);
      const float dz = __fsub_rn(H2, pos_l[j * 3 + 2]);
      float d2 = __fadd_rn(__fadd_rn(__fmul_rn(dx, dx), __fmul_rn(dy, dy)),
                           __fmul_rn(dz, dz));
      d2 = fmaxf(d2, 1e-16f);
      wk[k] = __frcp_rn(d2);
    }
    const float W  = __fadd_rn(__fadd_rn(wk[0], wk[1]), wk[2]);
    const float rW = __frcp_rn(W);
    #pragma unroll
    for (int k = 0; k < 3; ++k) {
      wn[tid * 3 + k] = wk[k] * rW;
      sj[tid * 3 + k] = jk[k];
    }
  }
  __syncthreads();

  const float4* __restrict__ x4   = (const float4*)x;
  float4* __restrict__       out4 = (float4*)out;
  #pragma unroll
  for (int i = 0; i < (FPB * NF4) / 1024; ++i) {
    const int task = tid + i * 1024;
    const int f    = task >> 6;
    const int cc   = task & 63;
    const int j0 = sj[f * 3 + 0], j1 = sj[f * 3 + 1], j2 = sj[f * 3 + 2];
    const float w0 = wn[f * 3 + 0], w1 = wn[f * 3 + 1], w2 = wn[f * 3 + 2];
    const float4 xa = x4[j0 * NF4 + cc];
    const float4 xb = x4[j1 * NF4 + cc];
    const float4 xc = x4[j2 * NF4 + cc];
    float4 r;
    r.x = xa.x * w0 + xb.x * w1 + xc.x * w2;
    r.y = xa.y * w0 + xb.y * w1 + xc.y * w2;
    r.z = xa.z * w0 + xb.z * w1 + xc.z * w2;
    r.w = xa.w * w0 + xb.w * w1 + xc.w * w2;
    out4[(blockIdx.x * FPB + f) * NF4 + cc] = r;
  }
}

// =================== fallback: round-5 single-kernel path ===================
__global__ __launch_bounds__(256)
void fb_prep_kernel(const float* __restrict__ pos_l, float4* __restrict__ cand)
{
  const int i = blockIdx.x * 256 + threadIdx.x;
  const float l0 = pos_l[i * 3 + 0];
  const float l1 = pos_l[i * 3 + 1];
  const float l2 = pos_l[i * 3 + 2];
  const float ll = __fadd_rn(__fadd_rn(__fmul_rn(l0, l0), __fmul_rn(l1, l1)),
                             __fmul_rn(l2, l2));
  cand[i] = make_float4(l0, l1, l2, ll);
}

__device__ __forceinline__ void fb_eval4(const v16f& s, int jb, const float h0,
    const float h1, const float h2, const float hh,
    float& b0, float& b1, float& b2, int& i0, int& i1, int& i2)
{
  #pragma unroll
  for (int i = 0; i < 4; ++i) {
    const float lx = s[i * 4 + 0], ly = s[i * 4 + 1];
    const float lz = s[i * 4 + 2], lw = s[i * 4 + 3];
    const float dot = __fmaf_rn(h2, lz, __fmaf_rn(h1, ly, __fmul_rn(h0, lx)));
    const float d   = __fadd_rn(__fsub_rn(hh, __fmul_rn(2.0f, dot)), lw);
    ins3(d, jb + i, b0, b1, b2, i0, i1, i2);
  }
}

__global__ __launch_bounds__(BLKF)
void fb_knn_kernel(const float* __restrict__ x,
                   const float* __restrict__ pos_l,
                   const float* __restrict__ pos_h,
                   const float* __restrict__ cand,
                   float* __restrict__ out)
{
  __shared__ float  pd[NWF * FPB * 3];
  __shared__ int    pj[NWF * FPB * 3];
  __shared__ float  wn[FPB * 3];
  __shared__ int    sj[FPB * 3];

  const int tid  = threadIdx.x;
  const int lane = tid & 63;
  const int wv   = __builtin_amdgcn_readfirstlane(tid >> 6);
  const int fg   = blockIdx.x * FPB + lane;

  const float h0 = pos_h[fg * 3 + 0];
  const float h1 = pos_h[fg * 3 + 1];
  const float h2 = pos_h[fg * 3 + 2];
  const float hh = __fadd_rn(__fadd_rn(__fmul_rn(h0, h0), __fmul_rn(h1, h1)),
                             __fmul_rn(h2, h2));

  float a0 = INFINITY, a1 = INFINITY, a2 = INFINITY;  int ai0 = 0, ai1 = 0, ai2 = 0;
  float c0 = INFINITY, c1 = INFINITY, c2 = INFINITY;  int ci0 = 0, ci1 = 0, ci2 = 0;

  const int jbase = __builtin_amdgcn_readfirstlane(wv * PERWF);

  for (int t = 0; t < PERWF; t += 16) {
    v16f sA, sB, sC, sD;
    const float* p = cand + (size_t)(jbase + t) * 4;
    asm volatile("s_load_dwordx16 %0, %4, 0x0\n\t"
                 "s_load_dwordx16 %1, %4, 0x40\n\t"
                 "s_load_dwordx16 %2, %4, 0x80\n\t"
                 "s_load_dwordx16 %3, %4, 0xc0"
                 : "=&s"(sA), "=&s"(sB), "=&s"(sC), "=&s"(sD)
                 : "s"(p));
    asm volatile("s_waitcnt lgkmcnt(0)"
                 : "+s"(sA), "+s"(sB), "+s"(sC), "+s"(sD));
    fb_eval4(sA, jbase + t +  0, h0, h1, h2, hh, a0, a1, a2, ai0, ai1, ai2);
    fb_eval4(sB, jbase + t +  4, h0, h1, h2, hh, a0, a1, a2, ai0, ai1, ai2);
    fb_eval4(sC, jbase + t +  8, h0, h1, h2, hh, c0, c1, c2, ci0, ci1, ci2);
    fb_eval4(sD, jbase + t + 12, h0, h1, h2, hh, c0, c1, c2, ci0, ci1, ci2);
  }

  lexins3(c0, ci0, a0, a1, a2, ai0, ai1, ai2);
  lexins3(c1, ci1, a0, a1, a2, ai0, ai1, ai2);
  lexins3(c2, ci2, a0, a1, a2, ai0, ai1, ai2);

  {
    const int s = (wv * FPB + lane) * 3;
    pd[s + 0] = a0; pd[s + 1] = a1; pd[s + 2] = a2;
    pj[s + 0] = ai0; pj[s + 1] = ai1; pj[s + 2] = ai2;
  }
  __syncthreads();

  if (tid < FPB) {
    float b0 = INFINITY, b1 = INFINITY, b2 = INFINITY;
    int   i0 = 0x7fffffff, i1 = 0x7fffffff, i2 = 0x7fffffff;
    for (int w = 0; w < NWF; ++w) {
      const int s = (w * FPB + tid) * 3;
      lexins3(pd[s + 0], pj[s + 0], b0, b1, b2, i0, i1, i2);
      lexins3(pd[s + 1], pj[s + 1], b0, b1, b2, i0, i1, i2);
      lexins3(pd[s + 2], pj[s + 2], b0, b1, b2, i0, i1, i2);
    }
    const int fm = blockIdx.x * FPB + tid;
    const float H0 = pos_h[fm * 3 + 0];
    const float H1 = pos_h[fm * 3 + 1];
    const float H2 = pos_h[fm * 3 + 2];
    float wk[3];
    int   jk[3] = { i0, i1, i2 };
    #pragma unroll
    for (int k = 0; k < 3; ++k) {
      const int j = jk[k];
      const float dx = __fsub_rn(H0, pos_l[j * 3 + 0]);
      const float dy = __fsub_rn(H1, pos_l[j * 3 + 1]);
      const float dz = __fsub_rn(H2, pos_l[j * 3 + 2]);
      float d2 = __fadd_rn(__fadd_rn(__fmul_rn(dx, dx), __fmul_rn(dy, dy)),
                           __fmul_rn(dz, dz));
      d2 = fmaxf(d2, 1e-16f);
      wk[k] = __frcp_rn(d2);
    }
    const float W  = __fadd_rn(__fadd_rn(wk[0], wk[1]), wk[2]);
    const float rW = __frcp_rn(W);
    #pragma unroll
    for (int k = 0; k < 3; ++k) {
      wn[tid * 3 + k] = wk[k] * rW;
      sj[tid * 3 + k] = jk[k];
    }
  }
  __syncthreads();

  const float4* __restrict__ x4   = (const float4*)x;
  float4* __restrict__       out4 = (float4*)out;
  #pragma unroll
  for (int i = 0; i < (FPB * NF4) / BLKF; ++i) {
    const int task = tid + i * BLKF;
    const int f    = task >> 6;
    const int cc   = task & 63;
    const int j0 = sj[f * 3 + 0], j1 = sj[f * 3 + 1], j2 = sj[f * 3 + 2];
    const float w0 = wn[f * 3 + 0], w1 = wn[f * 3 + 1], w2 = wn[f * 3 + 2];
    const float4 xa = x4[j0 * NF4 + cc];
    const float4 xb = x4[j1 * NF4 + cc];
    const float4 xc = x4[j2 * NF4 + cc];
    float4 r;
    r.x = xa.x * w0 + xb.x * w1 + xc.x * w2;
    r.y = xa.y * w0 + xb.y * w1 + xc.y * w2;
    r.z = xa.z * w0 + xb.z * w1 + xc.z * w2;
    r.w = xa.w * w0 + xb.w * w1 + xc.w * w2;
    out4[(blockIdx.x * FPB + f) * NF4 + cc] = r;
  }
}

extern "C" void kernel_launch(void* const* d_in, const int* in_sizes, int n_in,
                              void* d_out, int out_size, void* d_ws, size_t ws_size,
                              hipStream_t stream)
{
  const float* x     = (const float*)d_in[0];   // [4096, 256]
  const float* pos_l = (const float*)d_in[1];   // [4096, 3]
  const float* pos_h = (const float*)d_in[2];   // [16384, 3]
  float* out = (float*)d_out;                   // [16384, 256]

  const size_t need = (size_t)(4 * NL) * 4            // SoA cand      64 KB
                    + (size_t)(2 * NH * 3) * 4 * 2;   // pdist+pidx   768 KB

  if (ws_size >= need) {
    float* cand  = (float*)d_ws;                 // SoA: x|y|z|ll
    float* pdist = cand + 4 * NL;                // [2*NH*3]
    int*   pidx  = (int*)(pdist + 2 * NH * 3);   // [2*NH*3]
    hipLaunchKernelGGL(prep_soa_kernel, dim3(NL / 256), dim3(256), 0, stream,
                       pos_l, cand);
    hipLaunchKernelGGL(knn_scan_kernel, dim3((NH / FPB) * 2), dim3(BLKA), 0,
                       stream, pos_h, cand, pdist, pidx);
    hipLaunchKernelGGL(knn_finish_kernel, dim3(NH / FPB), dim3(1024), 0,
                       stream, x, pos_l, pos_h, pdist, pidx, out);
  } else {
    // fallback: round-5 single-kernel path (needs only 64 KB ws)
    float* cand = (float*)d_ws;
    hipLaunchKernelGGL(fb_prep_kernel, dim3(NL / 256), dim3(256), 0, stream,
                       pos_l, (float4*)cand);
    hipLaunchKernelGGL(fb_knn_kernel, dim3(NH / FPB), dim3(BLKF), 0, stream,
                       x, pos_l, pos_h, cand, out);
  }
}

// Round 8
// 99.380 us; speedup vs baseline: 1.1616x; 1.1616x over previous
//
#include <hip/hip_runtime.h>
#include <math.h>

#define NL    4096      // coarse points
#define NH    16384     // fine points
#define NF4   64        // 256 features / 4
#define BLK   1024      // threads (16 waves)
#define NW    16
#define FPB   64        // fine points per block (lane = fine point)
#define PERW  (NL / NW) // 256 candidates per wave
#define TOPM  6         // quantized-key shortlist size per list

typedef float v16f __attribute__((ext_vector_type(16)));
typedef float v2f  __attribute__((ext_vector_type(2)));

// ---- u32 sorted top-6 primitives (keys: float-bits|index, all distinct) ----
__device__ __forceinline__ unsigned int med3u(unsigned int a, unsigned int b,
                                              unsigned int c)
{
  unsigned int d;
  asm("v_med3_u32 %0, %1, %2, %3" : "=v"(d) : "v"(a), "v"(b), "v"(c));
  return d;
}
__device__ __forceinline__ unsigned int minu(unsigned int a, unsigned int b)
{
  unsigned int d;
  asm("v_min_u32 %0, %1, %2" : "=v"(d) : "v"(a), "v"(b));
  return d;
}
// Sorted insert of k into b0<=...<=b5: 6 independent ops, no cmp/cndmask.
__device__ __forceinline__ void ins6(unsigned int k,
    unsigned int& b0, unsigned int& b1, unsigned int& b2,
    unsigned int& b3, unsigned int& b4, unsigned int& b5)
{
  const unsigned int n0 = minu(b0, k);
  const unsigned int n1 = med3u(k, b0, b1);
  const unsigned int n2 = med3u(k, b1, b2);
  const unsigned int n3 = med3u(k, b2, b3);
  const unsigned int n4 = med3u(k, b3, b4);
  const unsigned int n5 = med3u(k, b4, b5);
  b0 = n0; b1 = n1; b2 = n2; b3 = n3; b4 = n4; b5 = n5;
}

// Lexicographic (d, j) insert for the exact fp32 rescore (top-3).
__device__ __forceinline__ void lexins3(float d, int j,
    float& b0, float& b1, float& b2, int& i0, int& i1, int& i2)
{
  bool s2 = (d < b2) || ((d == b2) && (j < i2));
  b2 = s2 ? d : b2;  i2 = s2 ? j : i2;
  bool s1 = (b2 < b1) || ((b2 == b1) && (i2 < i1));
  float tf = b1; int ti = i1;
  b1 = s1 ? b2 : b1;  i1 = s1 ? i2 : i1;
  b2 = s1 ? tf : b2;  i2 = s1 ? ti : i2;
  bool s0 = (b1 < b0) || ((b1 == b0) && (i1 < i0));
  tf = b0; ti = i0;
  b0 = s0 ? b1 : b0;  i0 = s0 ? i1 : i0;
  b1 = s0 ? tf : b1;  i1 = s0 ? ti : i1;
}

// Packed distance for 2 adjacent candidates (verified bit-identical in R7):
//   dot = fma(h2,lz, fma(h1,ly, mul(h0,lx)))
//   d2  = add( fma(dot,-2,hh), ll )
__device__ __forceinline__ v2f dist2_pk(v2f lx, v2f ly, v2f lz, v2f ll,
                                        v2f h00, v2f h11, v2f h22, v2f hhh,
                                        v2f m22)
{
  v2f d;
  asm("v_pk_mul_f32 %0, %1, %2\n\t"
      "v_pk_fma_f32 %0, %3, %4, %0\n\t"
      "v_pk_fma_f32 %0, %5, %6, %0\n\t"
      "v_pk_fma_f32 %0, %0, %7, %8\n\t"
      "v_pk_add_f32 %0, %0, %9"
      : "=&v"(d)
      : "v"(h00), "s"(lx), "v"(h11), "s"(ly), "v"(h22), "s"(lz),
        "v"(m22), "v"(hhh), "s"(ll));
  return d;
}

// ---------- prologue: SoA pack (x | y | z | ll), exact np rounding ----------
__global__ __launch_bounds__(256)
void prep_soa_kernel(const float* __restrict__ pos_l, float* __restrict__ cand)
{
  const int i = blockIdx.x * 256 + threadIdx.x;   // 0..NL-1
  const float l0 = pos_l[i * 3 + 0];
  const float l1 = pos_l[i * 3 + 1];
  const float l2 = pos_l[i * 3 + 2];
  const float ll = __fadd_rn(__fadd_rn(__fmul_rn(l0, l0), __fmul_rn(l1, l1)),
                             __fmul_rn(l2, l2));
  cand[i]          = l0;
  cand[NL + i]     = l1;
  cand[2 * NL + i] = l2;
  cand[3 * NL + i] = ll;
}

// ---------- main: quantized-key scan + exact rescore + interpolate ----------
__global__ __launch_bounds__(BLK)
void knn_interp_kernel(const float* __restrict__ x,
                       const float* __restrict__ pos_l,
                       const float* __restrict__ pos_h,
                       const float* __restrict__ cand,   // SoA x|y|z|ll
                       float* __restrict__ out)
{
  __shared__ unsigned int pk_[NW * FPB * TOPM];   // 24 KB partial shortlists
  __shared__ float wn[FPB * 3];
  __shared__ int   sj[FPB * 3];

  const int tid  = threadIdx.x;
  const int lane = tid & 63;
  const int wv   = __builtin_amdgcn_readfirstlane(tid >> 6);
  const int fg   = blockIdx.x * FPB + lane;

  const float h0 = pos_h[fg * 3 + 0];
  const float h1 = pos_h[fg * 3 + 1];
  const float h2 = pos_h[fg * 3 + 2];
  const float hh = __fadd_rn(__fadd_rn(__fmul_rn(h0, h0), __fmul_rn(h1, h1)),
                             __fmul_rn(h2, h2));
  const v2f h00 = { h0, h0 }, h11 = { h1, h1 }, h22 = { h2, h2 };
  const v2f hhh = { hh, hh }, m22 = { -2.0f, -2.0f };

  // key mask in a VGPR so v_and_or_b32 has only 1 scalar operand (j)
  unsigned int kmaskv;
  asm("v_mov_b32 %0, 0xfffff000" : "=v"(kmaskv));

  // two independent sorted top-6 key sets (even / odd pair halves)
  unsigned int a0 = ~0u, a1 = ~0u, a2 = ~0u, a3 = ~0u, a4 = ~0u, a5 = ~0u;
  unsigned int c0 = ~0u, c1 = ~0u, c2 = ~0u, c3 = ~0u, c4 = ~0u, c5 = ~0u;

  const int jbase = __builtin_amdgcn_readfirstlane(wv * PERW);

  for (int t = 0; t < PERW; t += 16) {
    v16f sx, sy, sz, sw;
    const float* p = cand + jbase + t;   // wave-uniform; SoA arrays 0x4000 apart
    asm volatile("s_load_dwordx16 %0, %4, 0x0\n\t"
                 "s_load_dwordx16 %1, %4, 0x4000\n\t"
                 "s_load_dwordx16 %2, %4, 0x8000\n\t"
                 "s_load_dwordx16 %3, %4, 0xc000"
                 : "=&s"(sx), "=&s"(sy), "=&s"(sz), "=&s"(sw)
                 : "s"(p));
    asm volatile("s_waitcnt lgkmcnt(0)"
                 : "+s"(sx), "+s"(sy), "+s"(sz), "+s"(sw));

    #pragma unroll
    for (int pr = 0; pr < 8; ++pr) {
      const v2f lx = { sx[2 * pr], sx[2 * pr + 1] };
      const v2f ly = { sy[2 * pr], sy[2 * pr + 1] };
      const v2f lz = { sz[2 * pr], sz[2 * pr + 1] };
      const v2f lw = { sw[2 * pr], sw[2 * pr + 1] };
      const v2f d  = dist2_pk(lx, ly, lz, lw, h00, h11, h22, hhh, m22);
      // clamp negatives to +0 for KEY ordering only (exact rescore later)
      const float dx0 = fmaxf(d.x, 0.0f);
      const float dy0 = fmaxf(d.y, 0.0f);
      const int j0 = jbase + t + 2 * pr;       // uniform (SALU)
      const int j1 = j0 + 1;
      unsigned int k0, k1;
      asm("v_and_or_b32 %0, %1, %2, %3"
          : "=v"(k0) : "v"(dx0), "v"(kmaskv), "s"(j0));
      asm("v_and_or_b32 %0, %1, %2, %3"
          : "=v"(k1) : "v"(dy0), "v"(kmaskv), "s"(j1));
      ins6(k0, a0, a1, a2, a3, a4, a5);
      ins6(k1, c0, c1, c2, c3, c4, c5);
    }
  }

  // merge odd-set into even-set (value-based, order-independent)
  ins6(c0, a0, a1, a2, a3, a4, a5);
  ins6(c1, a0, a1, a2, a3, a4, a5);
  ins6(c2, a0, a1, a2, a3, a4, a5);
  ins6(c3, a0, a1, a2, a3, a4, a5);
  ins6(c4, a0, a1, a2, a3, a4, a5);
  ins6(c5, a0, a1, a2, a3, a4, a5);

  {
    const int s = (wv * FPB + lane) * TOPM;
    pk_[s + 0] = a0; pk_[s + 1] = a1; pk_[s + 2] = a2;
    pk_[s + 3] = a3; pk_[s + 4] = a4; pk_[s + 5] = a5;
  }
  __syncthreads();

  // first 64 threads: merge NW shortlists, exact rescore, weights
  if (tid < FPB) {
    unsigned int m0 = ~0u, m1 = ~0u, m2 = ~0u, m3 = ~0u, m4 = ~0u, m5 = ~0u;
    for (int w = 0; w < NW; ++w) {
      const int s = (w * FPB + tid) * TOPM;
      #pragma unroll
      for (int q = 0; q < TOPM; ++q)
        ins6(pk_[s + q], m0, m1, m2, m3, m4, m5);
    }

    // exact fp32 expansion-form rescore of the 6 survivors; pick top-3
    // lexicographically — matches the reference's stable top_k exactly.
    const float b_hh = hh;   // this thread's own fine point (lane==tid)
    float e0 = INFINITY, e1 = INFINITY, e2 = INFINITY;
    int   i0 = 0x7fffffff, i1 = 0x7fffffff, i2 = 0x7fffffff;
    const unsigned int mk[TOPM] = { m0, m1, m2, m3, m4, m5 };
    #pragma unroll
    for (int q = 0; q < TOPM; ++q) {
      const int j = (int)(mk[q] & 0xFFFu);
      const float lx = cand[j];
      const float ly = cand[NL + j];
      const float lz = cand[2 * NL + j];
      const float ll = cand[3 * NL + j];   // exact np-rounded |l|^2 from prep
      const float dot = __fmaf_rn(h2, lz, __fmaf_rn(h1, ly, __fmul_rn(h0, lx)));
      const float d2  = __fadd_rn(__fsub_rn(b_hh, __fmul_rn(2.0f, dot)), ll);
      lexins3(d2, j, e0, e1, e2, i0, i1, i2);
    }

    // weights: exact diff-form recompute per reference
    const int fm = blockIdx.x * FPB + tid;
    const float H0 = pos_h[fm * 3 + 0];
    const float H1 = pos_h[fm * 3 + 1];
    const float H2 = pos_h[fm * 3 + 2];
    float wk[3];
    int   jk[3] = { i0, i1, i2 };
    #pragma unroll
    for (int k = 0; k < 3; ++k) {
      const int j = jk[k];
      const float dx = __fsub_rn(H0, pos_l[j * 3 + 0]);
      const float dy = __fsub_rn(H1, pos_l[j * 3 + 1]);
      const float dz = __fsub_rn(H2, pos_l[j * 3 + 2]);
      float d2 = __fadd_rn(__fadd_rn(__fmul_rn(dx, dx), __fmul_rn(dy, dy)),
                           __fmul_rn(dz, dz));
      d2 = fmaxf(d2, 1e-16f);
      wk[k] = __frcp_rn(d2);
    }
    const float W  = __fadd_rn(__fadd_rn(wk[0], wk[1]), wk[2]);
    const float rW = __frcp_rn(W);
    #pragma unroll
    for (int k = 0; k < 3; ++k) {
      wn[tid * 3 + k] = wk[k] * rW;
      sj[tid * 3 + k] = jk[k];
    }
  }
  __syncthreads();

  // interpolation: 64 fine x 64 float4 = 4096 tasks, 4 per thread
  const float4* __restrict__ x4   = (const float4*)x;
  float4* __restrict__       out4 = (float4*)out;
  #pragma unroll
  for (int i = 0; i < (FPB * NF4) / BLK; ++i) {
    const int task = tid + i * BLK;
    const int f    = task >> 6;
    const int cc   = task & 63;
    const int j0 = sj[f * 3 + 0], j1 = sj[f * 3 + 1], j2 = sj[f * 3 + 2];
    const float w0 = wn[f * 3 + 0], w1 = wn[f * 3 + 1], w2 = wn[f * 3 + 2];
    const float4 xa = x4[j0 * NF4 + cc];
    const float4 xb = x4[j1 * NF4 + cc];
    const float4 xc = x4[j2 * NF4 + cc];
    float4 r;
    r.x = xa.x * w0 + xb.x * w1 + xc.x * w2;
    r.y = xa.y * w0 + xb.y * w1 + xc.y * w2;
    r.z = xa.z * w0 + xb.z * w1 + xc.z * w2;
    r.w = xa.w * w0 + xb.w * w1 + xc.w * w2;
    out4[(blockIdx.x * FPB + f) * NF4 + cc] = r;
  }
}

extern "C" void kernel_launch(void* const* d_in, const int* in_sizes, int n_in,
                              void* d_out, int out_size, void* d_ws, size_t ws_size,
                              hipStream_t stream)
{
  const float* x     = (const float*)d_in[0];   // [4096, 256]
  const float* pos_l = (const float*)d_in[1];   // [4096, 3]
  const float* pos_h = (const float*)d_in[2];   // [16384, 3]
  float* out  = (float*)d_out;                  // [16384, 256]
  float* cand = (float*)d_ws;                   // SoA x|y|z|ll, 64 KB

  hipLaunchKernelGGL(prep_soa_kernel, dim3(NL / 256), dim3(256), 0, stream,
                     pos_l, cand);
  hipLaunchKernelGGL(knn_interp_kernel, dim3(NH / FPB), dim3(BLK), 0, stream,
                     x, pos_l, pos_h, cand, out);
}

// Round 9
// 91.982 us; speedup vs baseline: 1.2550x; 1.0804x over previous
//
#include <hip/hip_runtime.h>
#include <math.h>

#define NL    4096      // coarse points
#define NH    16384     // fine points
#define NF4   64        // 256 features / 4
#define BLK   1024      // threads (16 waves)
#define NW    16
#define FPB   64        // fine points per block (lane = fine point)
#define PERW  (NL / NW) // 256 candidates per wave
#define TOPM  5         // quantized-key shortlist size per list
#define SENT  0x7fffffff // signed-max sentinel (sorts last in i32 order)

typedef float v8f __attribute__((ext_vector_type(8)));
typedef float v2f __attribute__((ext_vector_type(2)));

// ---- i32 sorted top-5 primitives. Keys = (float-bits & 0xFFFFF000) | j.
// i32 ordering puts negative-d2 keys (rounding noise near 0) FIRST — no clamp
// needed. All real keys are distinct (index in low 12 bits).
__device__ __forceinline__ int med3i(int a, int b, int c)
{
  int d;
  asm("v_med3_i32 %0, %1, %2, %3" : "=v"(d) : "v"(a), "v"(b), "v"(c));
  return d;
}
__device__ __forceinline__ int mini(int a, int b)
{
  int d;
  asm("v_min_i32 %0, %1, %2" : "=v"(d) : "v"(a), "v"(b));
  return d;
}
// Sorted insert of k into b0<=...<=b4 (i32 order): 5 independent ops.
__device__ __forceinline__ void ins5(int k, int& b0, int& b1, int& b2,
                                     int& b3, int& b4)
{
  const int n0 = mini(b0, k);
  const int n1 = med3i(k, b0, b1);
  const int n2 = med3i(k, b1, b2);
  const int n3 = med3i(k, b2, b3);
  const int n4 = med3i(k, b3, b4);
  b0 = n0; b1 = n1; b2 = n2; b3 = n3; b4 = n4;
}

// Lexicographic (d, j) insert for the exact fp32 rescore (top-3).
__device__ __forceinline__ void lexins3(float d, int j,
    float& b0, float& b1, float& b2, int& i0, int& i1, int& i2)
{
  bool s2 = (d < b2) || ((d == b2) && (j < i2));
  b2 = s2 ? d : b2;  i2 = s2 ? j : i2;
  bool s1 = (b2 < b1) || ((b2 == b1) && (i2 < i1));
  float tf = b1; int ti = i1;
  b1 = s1 ? b2 : b1;  i1 = s1 ? i2 : i1;
  b2 = s1 ? tf : b2;  i2 = s1 ? ti : i2;
  bool s0 = (b1 < b0) || ((b1 == b0) && (i1 < i0));
  tf = b0; ti = i0;
  b0 = s0 ? b1 : b0;  i0 = s0 ? i1 : i0;
  b1 = s0 ? tf : b1;  i1 = s0 ? ti : i1;
}

// Packed distance for 2 adjacent candidates (bit-identical per component to
// the reference sequence; fma(dot,-2,hh) == sub(hh,mul(2,dot)) as 2*dot exact)
__device__ __forceinline__ v2f dist2_pk(v2f lx, v2f ly, v2f lz, v2f ll,
                                        v2f h00, v2f h11, v2f h22, v2f hhh,
                                        v2f m22)
{
  v2f d;
  asm("v_pk_mul_f32 %0, %1, %2\n\t"
      "v_pk_fma_f32 %0, %3, %4, %0\n\t"
      "v_pk_fma_f32 %0, %5, %6, %0\n\t"
      "v_pk_fma_f32 %0, %0, %7, %8\n\t"
      "v_pk_add_f32 %0, %0, %9"
      : "=&v"(d)
      : "v"(h00), "s"(lx), "v"(h11), "s"(ly), "v"(h22), "s"(lz),
        "v"(m22), "v"(hhh), "s"(ll));
  return d;
}

// 8-candidate SMEM chunk load: one s_load_dwordx8 per SoA array.
#define LOADCH(X, Y, Z, W, P)                                   \
  asm volatile("s_load_dwordx8 %0, %4, 0x0\n\t"                 \
               "s_load_dwordx8 %1, %4, 0x4000\n\t"              \
               "s_load_dwordx8 %2, %4, 0x8000\n\t"              \
               "s_load_dwordx8 %3, %4, 0xc000"                  \
               : "=&s"(X), "=&s"(Y), "=&s"(Z), "=&s"(W)         \
               : "s"(P))
// Wait-all (SMEM returns OOO — partial lgkm counts unsafe), dataflow-tied.
#define WAITCH(X, Y, Z, W)                                      \
  asm volatile("s_waitcnt lgkmcnt(0)"                           \
               : "+s"(X), "+s"(Y), "+s"(Z), "+s"(W))

// ---------- prologue: SoA pack (x | y | z | ll), exact np rounding ----------
__global__ __launch_bounds__(256)
void prep_soa_kernel(const float* __restrict__ pos_l, float* __restrict__ cand)
{
  const int i = blockIdx.x * 256 + threadIdx.x;   // 0..NL-1
  const float l0 = pos_l[i * 3 + 0];
  const float l1 = pos_l[i * 3 + 1];
  const float l2 = pos_l[i * 3 + 2];
  const float ll = __fadd_rn(__fadd_rn(__fmul_rn(l0, l0), __fmul_rn(l1, l1)),
                             __fmul_rn(l2, l2));
  cand[i]          = l0;
  cand[NL + i]     = l1;
  cand[2 * NL + i] = l2;
  cand[3 * NL + i] = ll;
}

// ---------- main: pipelined quantized-key scan + exact rescore ----------
__global__ __launch_bounds__(BLK)
void knn_interp_kernel(const float* __restrict__ x,
                       const float* __restrict__ pos_l,
                       const float* __restrict__ pos_h,
                       const float* __restrict__ cand,   // SoA x|y|z|ll
                       float* __restrict__ out)
{
  __shared__ int   pk_[NW * FPB * TOPM];   // 20 KB partial shortlists
  __shared__ float wn[FPB * 3];
  __shared__ int   sj[FPB * 3];

  const int tid  = threadIdx.x;
  const int lane = tid & 63;
  const int wv   = __builtin_amdgcn_readfirstlane(tid >> 6);
  const int fg   = blockIdx.x * FPB + lane;

  const float h0 = pos_h[fg * 3 + 0];
  const float h1 = pos_h[fg * 3 + 1];
  const float h2 = pos_h[fg * 3 + 2];
  const float hh = __fadd_rn(__fadd_rn(__fmul_rn(h0, h0), __fmul_rn(h1, h1)),
                             __fmul_rn(h2, h2));
  const v2f h00 = { h0, h0 }, h11 = { h1, h1 }, h22 = { h2, h2 };
  const v2f hhh = { hh, hh }, m22 = { -2.0f, -2.0f };

  // key mask in a VGPR so v_and_or_b32 keeps its single scalar operand for j
  unsigned int kmaskv;
  asm("v_mov_b32 %0, 0xfffff000" : "=v"(kmaskv));

  // two independent sorted top-5 key sets (even / odd pair slots)
  int a0 = SENT, a1 = SENT, a2 = SENT, a3 = SENT, a4 = SENT;
  int c0 = SENT, c1 = SENT, c2 = SENT, c3 = SENT, c4 = SENT;

  const int jbase = __builtin_amdgcn_readfirstlane(wv * PERW);

#define EVAL8(X, Y, Z, W, JB)                                              \
  do {                                                                     \
    _Pragma("unroll")                                                      \
    for (int pr = 0; pr < 4; ++pr) {                                       \
      const v2f lx = { X[2 * pr], X[2 * pr + 1] };                         \
      const v2f ly = { Y[2 * pr], Y[2 * pr + 1] };                         \
      const v2f lz = { Z[2 * pr], Z[2 * pr + 1] };                         \
      const v2f lw = { W[2 * pr], W[2 * pr + 1] };                         \
      const v2f d  = dist2_pk(lx, ly, lz, lw, h00, h11, h22, hhh, m22);    \
      const int j0 = (JB) + 2 * pr;                                        \
      const int j1 = j0 + 1;                                               \
      int k0, k1;                                                          \
      asm("v_and_or_b32 %0, %1, %2, %3"                                    \
          : "=v"(k0) : "v"(d.x), "v"(kmaskv), "s"(j0));                    \
      asm("v_and_or_b32 %0, %1, %2, %3"                                    \
          : "=v"(k1) : "v"(d.y), "v"(kmaskv), "s"(j1));                    \
      ins5(k0, a0, a1, a2, a3, a4);                                        \
      ins5(k1, c0, c1, c2, c3, c4);                                        \
    }                                                                      \
  } while (0)

  // software-pipelined scan: prefetch next 8-cand chunk before computing
  {
    v8f ax_, ay_, az_, aw_, bx_, by_, bz_, bw_;
    LOADCH(ax_, ay_, az_, aw_, cand + jbase);
    for (int t = 0; t < PERW; t += 16) {
      WAITCH(ax_, ay_, az_, aw_);                 // only A outstanding here
      LOADCH(bx_, by_, bz_, bw_, cand + jbase + t + 8);
      EVAL8(ax_, ay_, az_, aw_, jbase + t);
      WAITCH(bx_, by_, bz_, bw_);                 // only B outstanding here
      LOADCH(ax_, ay_, az_, aw_, cand + jbase + t + 16);  // last iter: reads
      EVAL8(bx_, by_, bz_, bw_, jbase + t + 8);   // past slice — never used
    }
  }
#undef EVAL8

  // merge odd-set into even-set (value-based, order-independent)
  ins5(c0, a0, a1, a2, a3, a4);
  ins5(c1, a0, a1, a2, a3, a4);
  ins5(c2, a0, a1, a2, a3, a4);
  ins5(c3, a0, a1, a2, a3, a4);
  ins5(c4, a0, a1, a2, a3, a4);

  {
    const int s = (wv * FPB + lane) * TOPM;
    pk_[s + 0] = a0; pk_[s + 1] = a1; pk_[s + 2] = a2;
    pk_[s + 3] = a3; pk_[s + 4] = a4;
  }
  __syncthreads();

  // first 64 threads: merge NW shortlists, exact rescore, weights
  if (tid < FPB) {
    int m0 = SENT, m1 = SENT, m2 = SENT, m3 = SENT, m4 = SENT;
    for (int w = 0; w < NW; ++w) {
      const int s = (w * FPB + tid) * TOPM;
      #pragma unroll
      for (int q = 0; q < TOPM; ++q)
        ins5(pk_[s + q], m0, m1, m2, m3, m4);
    }

    // exact fp32 expansion-form rescore of the 5 survivors; pick top-3
    // lexicographically — replicates the reference's stable top_k.
    float e0 = INFINITY, e1 = INFINITY, e2 = INFINITY;
    int   i0 = 0x7fffffff, i1 = 0x7fffffff, i2 = 0x7fffffff;
    const int mk[TOPM] = { m0, m1, m2, m3, m4 };
    #pragma unroll
    for (int q = 0; q < TOPM; ++q) {
      const int j = mk[q] & 0xFFF;
      const float lx = cand[j];
      const float ly = cand[NL + j];
      const float lz = cand[2 * NL + j];
      const float ll = cand[3 * NL + j];   // exact np-rounded |l|^2 from prep
      const float dot = __fmaf_rn(h2, lz, __fmaf_rn(h1, ly, __fmul_rn(h0, lx)));
      const float d2  = __fadd_rn(__fsub_rn(hh, __fmul_rn(2.0f, dot)), ll);
      lexins3(d2, j, e0, e1, e2, i0, i1, i2);
    }

    // weights: exact diff-form recompute per reference
    const int fm = blockIdx.x * FPB + tid;
    const float H0 = pos_h[fm * 3 + 0];
    const float H1 = pos_h[fm * 3 + 1];
    const float H2 = pos_h[fm * 3 + 2];
    float wk[3];
    int   jk[3] = { i0, i1, i2 };
    #pragma unroll
    for (int k = 0; k < 3; ++k) {
      const int j = jk[k];
      const float dx = __fsub_rn(H0, pos_l[j * 3 + 0]);
      const float dy = __fsub_rn(H1, pos_l[j * 3 + 1]);
      const float dz = __fsub_rn(H2, pos_l[j * 3 + 2]);
      float d2 = __fadd_rn(__fadd_rn(__fmul_rn(dx, dx), __fmul_rn(dy, dy)),
                           __fmul_rn(dz, dz));
      d2 = fmaxf(d2, 1e-16f);
      wk[k] = __frcp_rn(d2);
    }
    const float W  = __fadd_rn(__fadd_rn(wk[0], wk[1]), wk[2]);
    const float rW = __frcp_rn(W);
    #pragma unroll
    for (int k = 0; k < 3; ++k) {
      wn[tid * 3 + k] = wk[k] * rW;
      sj[tid * 3 + k] = jk[k];
    }
  }
  __syncthreads();

  // interpolation: 64 fine x 64 float4 = 4096 tasks, 4 per thread
  const float4* __restrict__ x4   = (const float4*)x;
  float4* __restrict__       out4 = (float4*)out;
  #pragma unroll
  for (int i = 0; i < (FPB * NF4) / BLK; ++i) {
    const int task = tid + i * BLK;
    const int f    = task >> 6;
    const int cc   = task & 63;
    const int j0 = sj[f * 3 + 0], j1 = sj[f * 3 + 1], j2 = sj[f * 3 + 2];
    const float w0 = wn[f * 3 + 0], w1 = wn[f * 3 + 1], w2 = wn[f * 3 + 2];
    const float4 xa = x4[j0 * NF4 + cc];
    const float4 xb = x4[j1 * NF4 + cc];
    const float4 xc = x4[j2 * NF4 + cc];
    float4 r;
    r.x = xa.x * w0 + xb.x * w1 + xc.x * w2;
    r.y = xa.y * w0 + xb.y * w1 + xc.y * w2;
    r.z = xa.z * w0 + xb.z * w1 + xc.z * w2;
    r.w = xa.w * w0 + xb.w * w1 + xc.w * w2;
    out4[(blockIdx.x * FPB + f) * NF4 + cc] = r;
  }
}

extern "C" void kernel_launch(void* const* d_in, const int* in_sizes, int n_in,
                              void* d_out, int out_size, void* d_ws, size_t ws_size,
                              hipStream_t stream)
{
  const float* x     = (const float*)d_in[0];   // [4096, 256]
  const float* pos_l = (const float*)d_in[1];   // [4096, 3]
  const float* pos_h = (const float*)d_in[2];   // [16384, 3]
  float* out  = (float*)d_out;                  // [16384, 256]
  float* cand = (float*)d_ws;                   // SoA x|y|z|ll, 64 KB

  hipLaunchKernelGGL(prep_soa_kernel, dim3(NL / 256), dim3(256), 0, stream,
                     pos_l, cand);
  hipLaunchKernelGGL(knn_interp_kernel, dim3(NH / FPB), dim3(BLK), 0, stream,
                     x, pos_l, pos_h, cand, out);
}